// Round 2
// baseline (28.074 us; speedup 1.0000x reference)
//
#include <hip/hip_runtime.h>
#include <math.h>

// Dims fixed by reference setup_inputs():
//   x   : (NS=1024, NN=192) f32 in {-1,+1}
//   W2  : (DD=24)           f32
//   W3  : (DD, DD)          f32
//   phi : (NN, 2)           f32
//   nd  : (NN, NN)          i32 in [0, DD), SYMMETRIC (min(r, r.T))
// out  : (NS,) f32 = J2 + J3 + logmf
//
// c[j,r] = sum_i x_i [nd[i,j]==r]. With x in {±1}:
//   c[j,r] = 2*popcount(M[j][r] & P[n]) - popcount(M[j][r])
// where M[j][r] = bitmask over i of (nd[j,i]==r), P[n] = bitmask over i of (x[n,i]>0).
// out[n] = sum_j x_j*(0.5*<c_j,W2> + c_j^T W3 c_j) + sum_j log(phi[j, x_j>0])

#define NS 1024
#define NN 192
#define DD 24

typedef unsigned long long ull;

// ws layout: Mbuf [NN][DD][8] uints (147456 B), then Pd [6][NS] uints (24576 B)
#define M_WORDS (NN * DD * 8)

// Blocks 0..NN-1: build M masks for column j (= row j, nd symmetric).
// Blocks NN..NN+NS-1: pack x-sign bits for sample n and write out[n] = logmf[n].
__global__ __launch_bounds__(192) void prep_kernel(
    const float* __restrict__ x,
    const float* __restrict__ phi,
    const int*   __restrict__ nd,
    unsigned* __restrict__ Mbuf,
    unsigned* __restrict__ Pd,
    float* __restrict__ out)
{
    const int tid = threadIdx.x;   // 0..191
    const int wv  = tid >> 6;      // wave 0..2
    const int b   = blockIdx.x;

    if (b < NN) {
        const int j   = b;
        const int ndv = nd[j * NN + tid];   // coalesced row read
        #pragma unroll
        for (int r = 0; r < DD; ++r) {
            ull m = __ballot(ndv == r);
            if ((tid & 63) == 0) {
                unsigned* dst = &Mbuf[(j * DD + r) * 8 + 2 * wv];
                dst[0] = (unsigned)m;
                dst[1] = (unsigned)(m >> 32);
            }
        }
    } else {
        const int n   = b - NN;
        const float xv = x[n * NN + tid];
        const int bit  = (xv > 0.0f) ? 1 : 0;
        ull m = __ballot(bit);
        if ((tid & 63) == 0) {
            Pd[(2 * wv    ) * NS + n] = (unsigned)m;
            Pd[(2 * wv + 1) * NS + n] = (unsigned)(m >> 32);
        }
        // logmf: reference idx = (1+x)/2 -> x=+1 selects phi[:,1]
        float contrib = logf(phi[tid * 2 + bit]);
        __shared__ float red[3];
        #pragma unroll
        for (int off = 32; off >= 1; off >>= 1)
            contrib += __shfl_down(contrib, off, 64);
        if ((tid & 63) == 0) red[wv] = contrib;
        __syncthreads();
        if (tid == 0) out[n] = red[0] + red[1] + red[2];
    }
}

// Grid (NS/64, NN/4), block 256 = 4 waves. Wave w handles j = blockIdx.y*4+w,
// lanes = 64 consecutive samples. c[24] lives in VGPRs; M/W3/W2 ride the
// scalar pipe (uniform j via readfirstlane).
__global__ __launch_bounds__(256) void main_kernel(
    const float* __restrict__ W2,
    const float* __restrict__ W3,
    const unsigned* __restrict__ Mbuf,
    const unsigned* __restrict__ Pd,
    float* __restrict__ out)
{
    const int lane = threadIdx.x & 63;
    const int wv   = threadIdx.x >> 6;
    const int n    = blockIdx.x * 64 + lane;
    int j = blockIdx.y * 4 + wv;
    j = __builtin_amdgcn_readfirstlane(j);

    const unsigned p0 = Pd[0 * NS + n];
    const unsigned p1 = Pd[1 * NS + n];
    const unsigned p2 = Pd[2 * NS + n];
    const unsigned p3 = Pd[3 * NS + n];
    const unsigned p4 = Pd[4 * NS + n];
    const unsigned p5 = Pd[5 * NS + n];

    const unsigned* __restrict__ Mj = &Mbuf[j * DD * 8];

    float c[DD];
    #pragma unroll
    for (int r = 0; r < DD; ++r) {
        const unsigned m0 = Mj[r * 8 + 0];
        const unsigned m1 = Mj[r * 8 + 1];
        const unsigned m2 = Mj[r * 8 + 2];
        const unsigned m3 = Mj[r * 8 + 3];
        const unsigned m4 = Mj[r * 8 + 4];
        const unsigned m5 = Mj[r * 8 + 5];
        int pc = __popc(m0 & p0) + __popc(m1 & p1) + __popc(m2 & p2)
               + __popc(m3 & p3) + __popc(m4 & p4) + __popc(m5 & p5);
        // cnt is wave-uniform -> scalar s_bcnt path
        int cnt = __popcll(((ull)m1 << 32) | m0)
                + __popcll(((ull)m3 << 32) | m2)
                + __popcll(((ull)m5 << 32) | m4);
        c[r] = fmaf(2.0f, (float)pc, -(float)cnt);
    }

    float q = 0.0f, l2 = 0.0f;
    #pragma unroll
    for (int r = 0; r < DD; ++r) {
        float t = 0.0f;
        #pragma unroll
        for (int s = 0; s < DD; ++s) t = fmaf(W3[r * DD + s], c[s], t);
        q  = fmaf(c[r], t, q);
        l2 = fmaf(W2[r], c[r], l2);
    }

    // x[n,j] sign = bit j of P (uniform word select, cheap cndmask chain)
    const int w = j >> 5, bpos = j & 31;
    unsigned pw = (w == 0) ? p0 : (w == 1) ? p1 : (w == 2) ? p2
                : (w == 3) ? p3 : (w == 4) ? p4 : p5;
    const float xj = ((pw >> bpos) & 1u) ? 1.0f : -1.0f;

    const float contrib = xj * fmaf(0.5f, l2, q);
    unsafeAtomicAdd(&out[n], contrib);   // HW global_atomic_add_f32
}

extern "C" void kernel_launch(void* const* d_in, const int* in_sizes, int n_in,
                              void* d_out, int out_size, void* d_ws, size_t ws_size,
                              hipStream_t stream) {
    const float* x   = (const float*)d_in[0];
    const float* W2  = (const float*)d_in[1];
    const float* W3  = (const float*)d_in[2];
    const float* phi = (const float*)d_in[3];
    const int*   nd  = (const int*)d_in[4];
    float* out = (float*)d_out;

    unsigned* Mbuf = (unsigned*)d_ws;
    unsigned* Pd   = (unsigned*)d_ws + M_WORDS;

    // prep: masks (NN blocks) + x-bit packing / logmf (NS blocks)
    prep_kernel<<<NN + NS, 192, 0, stream>>>(x, phi, nd, Mbuf, Pd, out);
    // main: 16 sample-chunks x 48 j-groups, 4 waves/block (one j per wave)
    main_kernel<<<dim3(NS / 64, NN / 4), 256, 0, stream>>>(W2, W3, Mbuf, Pd, out);
}